// Round 14
// baseline (356.493 us; speedup 1.0000x reference)
//
#include <hip/hip_runtime.h>
#include <math.h>

// UniMP / TransformerConv x4 (heads=1), N=50000, E=1e6, D=64.
// R19: gemm software pipeline. Session ledger (R7b..R18 arithmetic) pins
//      gemm at ~37-40us/dispatch -- 6x its ~6us traffic roofline -- hidden
//      under the top-5 cutoff all session. Cause: 2 waves/SIMD and a serial
//      per-tile chain (hfrag load ~900cyc -> MFMA -> pack -> store). Fix:
//      prefetch tile t+1's hfrag (+ wave3 residual) BEFORE computing tile t,
//      and grid 512 -> 256 (1 blk/CU, ~12 tiles/blk: 2x wfrag amortization,
//      the factor R13's 1024-grid A/B proved matters).
//      attn / CSR / numerics identical to R18 (355.4us, absmax 0.125).

#define DD 64
#define NB_HIST 256

typedef __attribute__((ext_vector_type(8))) _Float16 h8;   // 8 f16 (4 VGPR)
typedef __attribute__((ext_vector_type(2))) _Float16 h2;
typedef __attribute__((ext_vector_type(4))) float f32x4;
typedef __attribute__((ext_vector_type(2))) float f32x2;

__device__ __forceinline__ unsigned short f2h(float f) {
    union { _Float16 h; unsigned short u; } c;
    c.h = (_Float16)f;
    return c.u;
}
__device__ __forceinline__ h2 u2h2(unsigned u) {
    union { unsigned u; h2 h; } c; c.u = u; return c.h;
}
__device__ __forceinline__ unsigned pk2u(float a, float b) {  // v_cvt_pkrtz_f16_f32
    union { decltype(__builtin_amdgcn_cvt_pkrtz(0.f, 0.f)) h; unsigned u; } c;
    c.h = __builtin_amdgcn_cvt_pkrtz(a, b);
    return c.u;
}

// ---------------- CSR build + prep (fused) ----------------
__global__ __launch_bounds__(1024) void hist_prep(
    const int* __restrict__ dst, unsigned* __restrict__ cb, int E, int nbw,
    const float* __restrict__ x, unsigned short* __restrict__ hbf, int nD,
    const float* __restrict__ W0, const float* __restrict__ W1,
    const float* __restrict__ W2, const float* __restrict__ W3,
    const float* __restrict__ Wqs, const float* __restrict__ Wks,
    const float* __restrict__ Wvs, const float* __restrict__ Wss,
    unsigned short* __restrict__ Wt) {
    extern __shared__ unsigned hist[];          // nbw words
    int blk = blockIdx.x;
    for (int w = threadIdx.x; w < nbw; w += blockDim.x) hist[w] = 0;
    __syncthreads();
    int chunk = (E + gridDim.x - 1) / gridDim.x;
    int beg = blk * chunk;
    int end = min(E, beg + chunk);
    for (int e = beg + (int)threadIdx.x; e < end; e += blockDim.x) {
        int d = dst[e];
        atomicAdd(&hist[d >> 1], (d & 1) ? 0x10000u : 1u);
    }
    __syncthreads();
    unsigned* out = cb + (size_t)blk * nbw;
    for (int w = threadIdx.x; w < nbw; w += blockDim.x) out[w] = hist[w];

    // ---- prep tail (grid-stride over x-convert + weight transposes) ----
    int total = nD + 16 * 4096;
    int stride = gridDim.x * blockDim.x;
    for (int i = blk * blockDim.x + threadIdx.x; i < total; i += stride) {
        if (i < nD) { hbf[i] = f2h(x[i]); continue; }
        int id = i - nD;
        int mat = id >> 12, rem = id & 4095;
        int nn = rem >> 6, kk = rem & 63;
        int layer = mat >> 2, wh = mat & 3;
        const float* W;
        if (layer == 0) W = wh == 0 ? W0 : wh == 1 ? W1 : wh == 2 ? W2 : W3;
        else {
            const float* base = wh == 0 ? Wqs : wh == 1 ? Wks : wh == 2 ? Wvs : Wss;
            W = base + (size_t)(layer - 1) * 4096;
        }
        float val = W[kk * 64 + nn];
        if (wh == 0) val *= 0.125f;       // fold 1/sqrt(64) into Wq
        Wt[id] = f2h(val);                // Wt[mat][n][k]
    }
}

// 16-wide register batches: 256 block-values cost ~16 round trips, not 256.
__global__ __launch_bounds__(256) void prefix_blk(unsigned* __restrict__ cb,
                                                  int* __restrict__ counts,
                                                  int nbw, int n) {
    int w = blockIdx.x * blockDim.x + threadIdx.x;
    if (w >= nbw) return;
    unsigned acc = 0;
#pragma unroll 1
    for (int c = 0; c < NB_HIST; c += 16) {
        unsigned t[16];
#pragma unroll
        for (int j = 0; j < 16; ++j) t[j] = cb[(size_t)(c + j) * nbw + w];
#pragma unroll
        for (int j = 0; j < 16; ++j) {
            unsigned v = t[j];
            cb[(size_t)(c + j) * nbw + w] = acc;   // exclusive prefix (packed)
            acc += v;                              // halves independent (<65536)
        }
    }
    counts[2 * w] = (int)(acc & 0xffffu);
    int b1 = 2 * w + 1;
    if (b1 < n) counts[b1] = (int)(acc >> 16);
}

__global__ __launch_bounds__(1024) void scan_local(const int* __restrict__ counts,
                                                   int* __restrict__ localscan,
                                                   int* __restrict__ blockSums, int n) {
    __shared__ int sh[1024];
    int i = blockIdx.x * 1024 + threadIdx.x;
    int val = (i < n) ? counts[i] : 0;
    sh[threadIdx.x] = val;
    __syncthreads();
    for (int off = 1; off < 1024; off <<= 1) {
        int t = (threadIdx.x >= off) ? sh[threadIdx.x - off] : 0;
        __syncthreads();
        sh[threadIdx.x] += t;
        __syncthreads();
    }
    if (i < n) localscan[i] = sh[threadIdx.x] - val;
    if (threadIdx.x == 1023) blockSums[blockIdx.x] = sh[1023];
}

// single-WAVE exclusive scan of block sums (nb <= 64; n=50000 -> 49)
__global__ __launch_bounds__(64) void scan_tops(int* __restrict__ blockSums, int nb) {
    int i = threadIdx.x;
    int val = (i < nb) ? blockSums[i] : 0;
    int s = val;
#pragma unroll
    for (int off = 1; off < 64; off <<= 1) {
        int t = __shfl_up(s, off, 64);
        if (i >= off) s += t;
    }
    if (i < nb) blockSums[i] = s - val;   // exclusive
}

__global__ void emit_rowptr(const int* __restrict__ localscan,
                            const int* __restrict__ blockSums,
                            int* __restrict__ row_ptr, int n, int E) {
    int i = blockIdx.x * blockDim.x + threadIdx.x;
    if (i < n) row_ptr[i] = localscan[i] + blockSums[i >> 10];
    if (i == 0) row_ptr[n] = E;
}

// col[] stores BYTE offset of the 128B fp8 kv row: src * 128.
__global__ __launch_bounds__(1024) void scatter2(const int* __restrict__ src,
                                                 const int* __restrict__ dst,
                                                 const unsigned* __restrict__ cb,
                                                 const int* __restrict__ row_ptr,
                                                 int* __restrict__ col, int E, int nbw) {
    extern __shared__ unsigned hist[];
    int blk = blockIdx.x;
    for (int w = threadIdx.x; w < nbw; w += blockDim.x) hist[w] = 0;
    __syncthreads();
    const unsigned* pref = cb + (size_t)blk * nbw;
    int chunk = (E + gridDim.x - 1) / gridDim.x;
    int beg = blk * chunk;
    int end = min(E, beg + chunk);
    for (int e = beg + (int)threadIdx.x; e < end; e += blockDim.x) {
        int d = dst[e];
        unsigned sh = (unsigned)(d & 1) * 16u;
        unsigned old = atomicAdd(&hist[d >> 1], 1u << sh);
        unsigned lr = (old >> sh) & 0xffffu;
        unsigned pre = (pref[d >> 1] >> sh) & 0xffffu;
        int slot = row_ptr[d] + (int)pre + (int)lr;
        __builtin_nontemporal_store(src[e] << 7, &col[slot]);
    }
}

// ---------------- MFMA projection (software-pipelined) ----------------
// Block = 4 waves; wave 0..3 -> Q,K,V,S. A = W (frags resident), B = h.
// Tile t+1's hfrag (+ wave3 residual) loads issue BEFORE tile t's compute,
// so the ~900cyc fetch overlaps MFMA+pack+store. Grid 256 = 1 blk/CU,
// ~12 tiles/blk (2x wfrag amortization vs 512).
__global__ __launch_bounds__(256) void gemm_mfma(
    const unsigned short* __restrict__ hbf, const unsigned short* __restrict__ Wt,
    const float* __restrict__ Bq, const float* __restrict__ Bk,
    const float* __restrict__ Bv, const float* __restrict__ Bs,
    int with_res,
    unsigned short* __restrict__ qO, unsigned char* __restrict__ kvO,
    unsigned short* __restrict__ sO, int ntiles) {
    int lane = threadIdx.x & 63;
    int wave = threadIdx.x >> 6;
    int ml = lane & 15, ql = lane >> 4;
    int gsz = gridDim.x;

    const unsigned short* W = Wt + wave * 4096;
    h8 wfrag[4][2];     // A-frag: A[m=ml][k=ql*8+j] = Wt[t*16+ml][kh*32+ql*8+j]
#pragma unroll
    for (int t = 0; t < 4; ++t)
#pragma unroll
        for (int kh = 0; kh < 2; ++kh)
            wfrag[t][kh] = *(const h8*)(W + (t * 16 + ml) * 64 + kh * 32 + ql * 8);

    const float* bias = wave == 0 ? Bq : wave == 1 ? Bk : wave == 2 ? Bv : Bs;
    float4 bias4[4];
#pragma unroll
    for (int t = 0; t < 4; ++t) {
        bias4[t] = *(const float4*)(bias + t * 16 + ql * 4);
        if (wave == 0) {
            bias4[t].x *= 0.125f; bias4[t].y *= 0.125f;
            bias4[t].z *= 0.125f; bias4[t].w *= 0.125f;
        }
    }

    bool resw = (with_res && wave == 3);
    int tile = blockIdx.x;
    if (tile >= ntiles) return;

    h8 hcur[2];
    uint2 rcur[4];
    {   // prologue: load first tile
        size_t re = (size_t)(tile * 16 + ml) * 64;
#pragma unroll
        for (int kh = 0; kh < 2; ++kh)
            hcur[kh] = *(const h8*)(hbf + re + kh * 32 + ql * 8);
        if (resw)
#pragma unroll
            for (int t = 0; t < 4; ++t)
                rcur[t] = *(const uint2*)(hbf + re + t * 16 + ql * 4);
    }

    while (tile < ntiles) {
        int nxt = tile + gsz;
        h8 hnext[2];
        uint2 rnext[4];
        if (nxt < ntiles) {               // prefetch next tile before compute
            size_t re = (size_t)(nxt * 16 + ml) * 64;
#pragma unroll
            for (int kh = 0; kh < 2; ++kh)
                hnext[kh] = *(const h8*)(hbf + re + kh * 32 + ql * 8);
            if (resw)
#pragma unroll
                for (int t = 0; t < 4; ++t)
                    rnext[t] = *(const uint2*)(hbf + re + t * 16 + ql * 4);
        }

        int node0 = tile * 16;
        f32x4 acc[4];
#pragma unroll
        for (int t = 0; t < 4; ++t) {
            acc[t][0] = bias4[t].x; acc[t][1] = bias4[t].y;
            acc[t][2] = bias4[t].z; acc[t][3] = bias4[t].w;
        }
#pragma unroll
        for (int t = 0; t < 4; ++t)
#pragma unroll
            for (int kh = 0; kh < 2; ++kh)
                acc[t] = __builtin_amdgcn_mfma_f32_16x16x32_f16(
                    wfrag[t][kh], hcur[kh], acc[t], 0, 0, 0);

        size_t rowe = (size_t)(node0 + ml) * 64;
        if (wave == 0) {
#pragma unroll
            for (int t = 0; t < 4; ++t) {
                uint2 st;
                st.x = pk2u(acc[t][0], acc[t][1]);
                st.y = pk2u(acc[t][2], acc[t][3]);
                *(uint2*)(qO + rowe + t * 16 + ql * 4) = st;
            }
        } else if (wave == 3) {
#pragma unroll
            for (int t = 0; t < 4; ++t) {
                float4 st = {acc[t][0], acc[t][1], acc[t][2], acc[t][3]};
                if (with_res) {
                    h2 r0 = u2h2(rcur[t].x), r1 = u2h2(rcur[t].y);
                    st.x += (float)r0[0]; st.y += (float)r0[1];
                    st.z += (float)r1[0]; st.w += (float)r1[1];
                }
                uint2 sp;
                sp.x = pk2u(st.x, st.y);
                sp.y = pk2u(st.z, st.w);
                *(uint2*)(sO + rowe + t * 16 + ql * 4) = sp;
            }
        } else {
            // dims [t*16+ql*4, +4) -> chunk = t*2 + (ql>>1), byte (ql&1)*4
            size_t kvr = (size_t)(node0 + ml) * 128 + (wave == 2 ? 8 : 0);
#pragma unroll
            for (int t = 0; t < 4; ++t) {
                int pk = __builtin_amdgcn_cvt_pk_fp8_f32(acc[t][0], acc[t][1], 0, false);
                pk = __builtin_amdgcn_cvt_pk_fp8_f32(acc[t][2], acc[t][3], pk, true);
                size_t addr = kvr + (size_t)(t * 2 + (ql >> 1)) * 16 + (ql & 1) * 4;
                *(unsigned*)(kvO + addr) = (unsigned)pk;
            }
        }

        hcur[0] = hnext[0]; hcur[1] = hnext[1];
        if (resw) {
#pragma unroll
            for (int t = 0; t < 4; ++t) rcur[t] = rnext[t];
        }
        tile = nxt;
    }
}

// ---------------- fused attention + LN ----------------
// One wave per dst node; 8 groups of 8 lanes; x2 volley (16 edge-slots).
// Byte-interleaved fp8 kv row: lane qi reads ONE uint4 (k-chunk | v-chunk).
// fp32 accum, LN+ReLU. fp32 out only for the final layer.
#define EDGE_COMP(U) do {                                                      \
    f32x2 k0 = __builtin_amdgcn_cvt_pk_f32_fp8((U).x, false);                  \
    f32x2 k1 = __builtin_amdgcn_cvt_pk_f32_fp8((U).x, true);                   \
    f32x2 k2 = __builtin_amdgcn_cvt_pk_f32_fp8((U).y, false);                  \
    f32x2 k3 = __builtin_amdgcn_cvt_pk_f32_fp8((U).y, true);                   \
    float d = qf0 * k0[0];                                                     \
    d = fmaf(qf1, k0[1], d); d = fmaf(qf2, k1[0], d); d = fmaf(qf3, k1[1], d); \
    d = fmaf(qf4, k2[0], d); d = fmaf(qf5, k2[1], d); d = fmaf(qf6, k3[0], d); \
    d = fmaf(qf7, k3[1], d);                                                   \
    d += __shfl_xor(d, 1); d += __shfl_xor(d, 2); d += __shfl_xor(d, 4);       \
    float p = __expf(d); ssum += p;                                            \
    f32x2 w0 = __builtin_amdgcn_cvt_pk_f32_fp8((U).z, false);                  \
    f32x2 w1 = __builtin_amdgcn_cvt_pk_f32_fp8((U).z, true);                   \
    f32x2 w2 = __builtin_amdgcn_cvt_pk_f32_fp8((U).w, false);                  \
    f32x2 w3 = __builtin_amdgcn_cvt_pk_f32_fp8((U).w, true);                   \
    aa.x = fmaf(w0[0], p, aa.x); aa.y = fmaf(w0[1], p, aa.y);                  \
    aa.z = fmaf(w1[0], p, aa.z); aa.w = fmaf(w1[1], p, aa.w);                  \
    ab.x = fmaf(w2[0], p, ab.x); ab.y = fmaf(w2[1], p, ab.y);                  \
    ab.z = fmaf(w3[0], p, ab.z); ab.w = fmaf(w3[1], p, ab.w);                  \
} while (0)

__global__ __launch_bounds__(256) void attn_agg_ln(
    const unsigned short* __restrict__ qh, const unsigned char* __restrict__ kv,
    const unsigned short* __restrict__ sk,
    const int* __restrict__ row_ptr, const int* __restrict__ col,
    const float* __restrict__ g, const float* __restrict__ b,
    float* __restrict__ out, unsigned short* __restrict__ hbf_out, int n) {
    int node = blockIdx.x * 4 + (threadIdx.x >> 6);
    int lane = threadIdx.x & 63;
    if (node >= n) return;
    int grp = lane >> 3;
    int qi = lane & 7;

    size_t ro = (size_t)node * DD + qi * 8;
    uint4 qu = *(const uint4*)(qh + ro);          // 8 f16, pre-scaled 1/8
    uint4 su = *(const uint4*)(sk + ro);          // 8 f16 skip(+residual)
    int beg = row_ptr[node], end = row_ptr[node + 1];

    // unpack q to 8 f32 once (feeds fp8-k fma chain)
    h2 q0 = u2h2(qu.x), q1 = u2h2(qu.y), q2 = u2h2(qu.z), q3 = u2h2(qu.w);
    float qf0 = (float)q0[0], qf1 = (float)q0[1], qf2 = (float)q1[0], qf3 = (float)q1[1];
    float qf4 = (float)q2[0], qf5 = (float)q2[1], qf6 = (float)q3[0], qf7 = (float)q3[1];

    float ssum = 0.0f;
    float4 aa = {0.f, 0.f, 0.f, 0.f}, ab = {0.f, 0.f, 0.f, 0.f};

    int e = beg + grp;
    int cv0 = (e < end) ? col[e] : -1;
    int cv1 = (e + 8 < end) ? col[e + 8] : -1;
    for (int e0 = beg; e0 < end; e0 += 16) {
        bool a0 = cv0 >= 0, a1 = cv1 >= 0;
        uint4 u0, u1;
        if (a0) u0 = *(const uint4*)(kv + cv0 + qi * 16);   // k|v chunk, one load
        if (a1) u1 = *(const uint4*)(kv + cv1 + qi * 16);
        e += 16;
        cv0 = (e < end) ? col[e] : -1;
        cv1 = (e + 8 < end) ? col[e + 8] : -1;
        if (a0) EDGE_COMP(u0);
        if (a1) EDGE_COMP(u1);
    }

#pragma unroll
    for (int off = 8; off <= 32; off <<= 1) {
        ssum += __shfl_xor(ssum, off);
        aa.x += __shfl_xor(aa.x, off); aa.y += __shfl_xor(aa.y, off);
        aa.z += __shfl_xor(aa.z, off); aa.w += __shfl_xor(aa.w, off);
        ab.x += __shfl_xor(ab.x, off); ab.y += __shfl_xor(ab.y, off);
        ab.z += __shfl_xor(ab.z, off); ab.w += __shfl_xor(ab.w, off);
    }
    float inv = (end > beg) ? 1.0f / ssum : 0.0f;
    aa.x *= inv; aa.y *= inv; aa.z *= inv; aa.w *= inv;
    ab.x *= inv; ab.y *= inv; ab.z *= inv; ab.w *= inv;

    {   // + skip (+ residual), f16 -> f32
        h2 t0 = u2h2(su.x), t1 = u2h2(su.y), t2 = u2h2(su.z), t3 = u2h2(su.w);
        aa.x += (float)t0[0]; aa.y += (float)t0[1];
        aa.z += (float)t1[0]; aa.w += (float)t1[1];
        ab.x += (float)t2[0]; ab.y += (float)t2[1];
        ab.z += (float)t3[0]; ab.w += (float)t3[1];
    }

    float s1 = aa.x + aa.y + aa.z + aa.w + ab.x + ab.y + ab.z + ab.w;
    s1 += __shfl_xor(s1, 1);
    s1 += __shfl_xor(s1, 2);
    s1 += __shfl_xor(s1, 4);
    float mu = s1 * (1.0f / DD);
    float dx0 = aa.x - mu, dx1 = aa.y - mu, dx2 = aa.z - mu, dx3 = aa.w - mu;
    float dx4 = ab.x - mu, dx5 = ab.y - mu, dx6 = ab.z - mu, dx7 = ab.w - mu;
    float s2v = dx0 * dx0 + dx1 * dx1 + dx2 * dx2 + dx3 * dx3
              + dx4 * dx4 + dx5 * dx5 + dx6 * dx6 + dx7 * dx7;
    s2v += __shfl_xor(s2v, 1);
    s2v += __shfl_xor(s2v, 2);
    s2v += __shfl_xor(s2v, 4);
    float var = s2v * (1.0f / DD);
    float is = rsqrtf(var + 1e-5f);
    float4 g4a = *(const float4*)(g + qi * 8);
    float4 g4b = *(const float4*)(g + qi * 8 + 4);
    float4 b4a = *(const float4*)(b + qi * 8);
    float4 b4b = *(const float4*)(b + qi * 8 + 4);
    float4 ya, yb;
    ya.x = fmaxf(dx0 * is * g4a.x + b4a.x, 0.0f);
    ya.y = fmaxf(dx1 * is * g4a.y + b4a.y, 0.0f);
    ya.z = fmaxf(dx2 * is * g4a.z + b4a.z, 0.0f);
    ya.w = fmaxf(dx3 * is * g4a.w + b4a.w, 0.0f);
    yb.x = fmaxf(dx4 * is * g4b.x + b4b.x, 0.0f);
    yb.y = fmaxf(dx5 * is * g4b.y + b4b.y, 0.0f);
    yb.z = fmaxf(dx6 * is * g4b.z + b4b.z, 0.0f);
    yb.w = fmaxf(dx7 * is * g4b.w + b4b.w, 0.0f);
    if (grp == 0) {
        if (out) {
            *(float4*)(out + ro) = ya;
            *(float4*)(out + ro + 4) = yb;
        }
        uint4 hv;
        hv.x = pk2u(ya.x, ya.y);
        hv.y = pk2u(ya.z, ya.w);
        hv.z = pk2u(yb.x, yb.y);
        hv.w = pk2u(yb.z, yb.w);
        *(uint4*)(hbf_out + ro) = hv;
    }
}

extern "C" void kernel_launch(void* const* d_in, const int* in_sizes, int n_in,
                              void* d_out, int out_size, void* d_ws, size_t ws_size,
                              hipStream_t stream) {
    const int D = DD;
    const float* x = (const float*)d_in[0];
    const int n = in_sizes[0] / D;       // 50000
    const int* ei = (const int*)d_in[1];
    const int E = in_sizes[1] / 2;       // 1e6
    const int* srcp = ei;
    const int* dstp = ei + E;
    const int nbw = (n + 1) / 2;         // bin-pair words (25000)

    static bool s_attr = false;
    if (!s_attr) {
        s_attr = true;
        (void)hipFuncSetAttribute((const void*)hist_prep,
                                  hipFuncAttributeMaxDynamicSharedMemorySize, 102400);
        (void)hipFuncSetAttribute((const void*)scatter2,
                                  hipFuncAttributeMaxDynamicSharedMemorySize, 102400);
    }

    char* wsp = (char*)d_ws;
    auto take = [&](size_t bytes) {
        char* p = wsp;
        wsp += (bytes + 255) & ~(size_t)255;
        return (void*)p;
    };
    int* counts    = (int*)take((size_t)n * 4);
    int* row_ptr   = (int*)take((size_t)(n + 1) * 4);
    unsigned* cb   = (unsigned*)take((size_t)NB_HIST * nbw * 4);   // 25.6 MB
    int* col       = (int*)take((size_t)E * 4);
    int* localscan = (int*)take((size_t)n * 4);
    int* blockSums = (int*)take((size_t)1024 * 4);
    size_t fsz = (size_t)n * D * 4;
    unsigned short* qb  = (unsigned short*)take(fsz / 2);   // f16 q (pre-scaled)
    unsigned char* kvb  = (unsigned char*)take(fsz / 2);    // fp8 k|v rows: n*128B
    unsigned short* sb  = (unsigned short*)take(fsz / 2);   // f16 skip+residual
    unsigned short* hbf = (unsigned short*)take(fsz / 2);   // f16 h (layer carrier)
    unsigned short* Wt  = (unsigned short*)take((size_t)16 * 4096 * 2);

    // ---- CSR build + prep (no global atomics) ----
    int tb = 256;
    size_t ldsH = (size_t)nbw * 4;       // 100 KB
    int nbScan = (n + 1023) / 1024;
    hist_prep<<<NB_HIST, 1024, ldsH, stream>>>(
        dstp, cb, E, nbw,
        x, hbf, n * D,
        (const float*)d_in[2], (const float*)d_in[4], (const float*)d_in[6],
        (const float*)d_in[8], (const float*)d_in[12], (const float*)d_in[14],
        (const float*)d_in[16], (const float*)d_in[18], Wt);
    prefix_blk<<<(nbw + tb - 1) / tb, tb, 0, stream>>>(cb, counts, nbw, n);
    scan_local<<<nbScan, 1024, 0, stream>>>(counts, localscan, blockSums, n);
    scan_tops<<<1, 64, 0, stream>>>(blockSums, nbScan);
    emit_rowptr<<<(n + tb - 1) / tb, tb, 0, stream>>>(localscan, blockSums, row_ptr, n, E);
    scatter2<<<NB_HIST, 1024, ldsH, stream>>>(srcp, dstp, cb, row_ptr, col, E, nbw);

    // ---- 4 conv layers ----
    int ntiles = n / 16;                 // 3125
    int nba = (n + 3) / 4;
    for (int layer = 0; layer < 4; ++layer) {
        const float *bq_, *bk_, *bv_, *bs_, *g_, *b_;
        if (layer == 0) {
            bq_ = (const float*)d_in[3];  bk_ = (const float*)d_in[5];
            bv_ = (const float*)d_in[7];  bs_ = (const float*)d_in[9];
            g_  = (const float*)d_in[10]; b_  = (const float*)d_in[11];
        } else {
            int i = layer - 1;
            bq_ = (const float*)d_in[13] + (size_t)i * D;
            bk_ = (const float*)d_in[15] + (size_t)i * D;
            bv_ = (const float*)d_in[17] + (size_t)i * D;
            bs_ = (const float*)d_in[19] + (size_t)i * D;
            g_  = (const float*)d_in[20] + (size_t)i * D;
            b_  = (const float*)d_in[21] + (size_t)i * D;
        }
        gemm_mfma<<<256, 256, 0, stream>>>(hbf, Wt + (size_t)layer * 4 * 4096,
                                           bq_, bk_, bv_, bs_,
                                           layer == 0 ? 0 : 1,
                                           qb, kvb, sb, ntiles);
        attn_agg_ln<<<nba, 256, 0, stream>>>(qb, kvb, sb, row_ptr, col, g_, b_,
                                             layer == 3 ? (float*)d_out : nullptr,
                                             hbf, n);
    }
}

// Round 15
// 353.108 us; speedup vs baseline: 1.0096x; 1.0096x over previous
//
#include <hip/hip_runtime.h>
#include <math.h>

// UniMP / TransformerConv x4 (heads=1), N=50000, E=1e6, D=64.
// R20: after two gemm-side nulls (R19 pipeline, R13 grid), revert gemm to
//      R18's exact best form (plain loop, grid 512). Attack what arithmetic
//      still supports:
//      - NB_HIST 256 -> 128: cb histogram buffer 25.6 -> 12.8MB, touched 3x
//        (hist dump, prefix r+w, scatter pref) => ~38MB less traffic, and
//        prefix_blk's serial batch count halves (16 -> 8 latency rounds).
//        Per-block edges 7813 < 65536, packing still safe.
//      - exp2 fold: Wq/bq pre-scale becomes 0.125*log2(e) so attn uses
//        exp2f(d) directly (drops the compiler's x*log2e mul per edge).
//      attn / layout / numerics otherwise identical to R18 (355.3us best).

#define DD 64
#define NB_HIST 128

typedef __attribute__((ext_vector_type(8))) _Float16 h8;   // 8 f16 (4 VGPR)
typedef __attribute__((ext_vector_type(2))) _Float16 h2;
typedef __attribute__((ext_vector_type(4))) float f32x4;
typedef __attribute__((ext_vector_type(2))) float f32x2;

#define QSCALE 0.18033688f   // (1/8) * log2(e): folded into Wq,bq at prep

__device__ __forceinline__ unsigned short f2h(float f) {
    union { _Float16 h; unsigned short u; } c;
    c.h = (_Float16)f;
    return c.u;
}
__device__ __forceinline__ h2 u2h2(unsigned u) {
    union { unsigned u; h2 h; } c; c.u = u; return c.h;
}
__device__ __forceinline__ unsigned pk2u(float a, float b) {  // v_cvt_pkrtz_f16_f32
    union { decltype(__builtin_amdgcn_cvt_pkrtz(0.f, 0.f)) h; unsigned u; } c;
    c.h = __builtin_amdgcn_cvt_pkrtz(a, b);
    return c.u;
}

// ---------------- CSR build + prep (fused) ----------------
__global__ __launch_bounds__(1024) void hist_prep(
    const int* __restrict__ dst, unsigned* __restrict__ cb, int E, int nbw,
    const float* __restrict__ x, unsigned short* __restrict__ hbf, int nD,
    const float* __restrict__ W0, const float* __restrict__ W1,
    const float* __restrict__ W2, const float* __restrict__ W3,
    const float* __restrict__ Wqs, const float* __restrict__ Wks,
    const float* __restrict__ Wvs, const float* __restrict__ Wss,
    unsigned short* __restrict__ Wt) {
    extern __shared__ unsigned hist[];          // nbw words
    int blk = blockIdx.x;
    for (int w = threadIdx.x; w < nbw; w += blockDim.x) hist[w] = 0;
    __syncthreads();
    int chunk = (E + gridDim.x - 1) / gridDim.x;
    int beg = blk * chunk;
    int end = min(E, beg + chunk);
    for (int e = beg + (int)threadIdx.x; e < end; e += blockDim.x) {
        int d = dst[e];
        atomicAdd(&hist[d >> 1], (d & 1) ? 0x10000u : 1u);
    }
    __syncthreads();
    unsigned* out = cb + (size_t)blk * nbw;
    for (int w = threadIdx.x; w < nbw; w += blockDim.x) out[w] = hist[w];

    // ---- prep tail (grid-stride over x-convert + weight transposes) ----
    int total = nD + 16 * 4096;
    int stride = gridDim.x * blockDim.x;
    for (int i = blk * blockDim.x + threadIdx.x; i < total; i += stride) {
        if (i < nD) { hbf[i] = f2h(x[i]); continue; }
        int id = i - nD;
        int mat = id >> 12, rem = id & 4095;
        int nn = rem >> 6, kk = rem & 63;
        int layer = mat >> 2, wh = mat & 3;
        const float* W;
        if (layer == 0) W = wh == 0 ? W0 : wh == 1 ? W1 : wh == 2 ? W2 : W3;
        else {
            const float* base = wh == 0 ? Wqs : wh == 1 ? Wks : wh == 2 ? Wvs : Wss;
            W = base + (size_t)(layer - 1) * 4096;
        }
        float val = W[kk * 64 + nn];
        if (wh == 0) val *= QSCALE;       // fold 1/sqrt(64)*log2(e) into Wq
        Wt[id] = f2h(val);                // Wt[mat][n][k]
    }
}

// 16-wide register batches; NB_HIST=128 -> 8 serial rounds.
__global__ __launch_bounds__(256) void prefix_blk(unsigned* __restrict__ cb,
                                                  int* __restrict__ counts,
                                                  int nbw, int n) {
    int w = blockIdx.x * blockDim.x + threadIdx.x;
    if (w >= nbw) return;
    unsigned acc = 0;
#pragma unroll 1
    for (int c = 0; c < NB_HIST; c += 16) {
        unsigned t[16];
#pragma unroll
        for (int j = 0; j < 16; ++j) t[j] = cb[(size_t)(c + j) * nbw + w];
#pragma unroll
        for (int j = 0; j < 16; ++j) {
            unsigned v = t[j];
            cb[(size_t)(c + j) * nbw + w] = acc;   // exclusive prefix (packed)
            acc += v;                              // halves independent (<65536)
        }
    }
    counts[2 * w] = (int)(acc & 0xffffu);
    int b1 = 2 * w + 1;
    if (b1 < n) counts[b1] = (int)(acc >> 16);
}

__global__ __launch_bounds__(1024) void scan_local(const int* __restrict__ counts,
                                                   int* __restrict__ localscan,
                                                   int* __restrict__ blockSums, int n) {
    __shared__ int sh[1024];
    int i = blockIdx.x * 1024 + threadIdx.x;
    int val = (i < n) ? counts[i] : 0;
    sh[threadIdx.x] = val;
    __syncthreads();
    for (int off = 1; off < 1024; off <<= 1) {
        int t = (threadIdx.x >= off) ? sh[threadIdx.x - off] : 0;
        __syncthreads();
        sh[threadIdx.x] += t;
        __syncthreads();
    }
    if (i < n) localscan[i] = sh[threadIdx.x] - val;
    if (threadIdx.x == 1023) blockSums[blockIdx.x] = sh[1023];
}

// single-WAVE exclusive scan of block sums (nb <= 64; n=50000 -> 49)
__global__ __launch_bounds__(64) void scan_tops(int* __restrict__ blockSums, int nb) {
    int i = threadIdx.x;
    int val = (i < nb) ? blockSums[i] : 0;
    int s = val;
#pragma unroll
    for (int off = 1; off < 64; off <<= 1) {
        int t = __shfl_up(s, off, 64);
        if (i >= off) s += t;
    }
    if (i < nb) blockSums[i] = s - val;   // exclusive
}

__global__ void emit_rowptr(const int* __restrict__ localscan,
                            const int* __restrict__ blockSums,
                            int* __restrict__ row_ptr, int n, int E) {
    int i = blockIdx.x * blockDim.x + threadIdx.x;
    if (i < n) row_ptr[i] = localscan[i] + blockSums[i >> 10];
    if (i == 0) row_ptr[n] = E;
}

// col[] stores BYTE offset of the 128B fp8 kv row: src * 128.
__global__ __launch_bounds__(1024) void scatter2(const int* __restrict__ src,
                                                 const int* __restrict__ dst,
                                                 const unsigned* __restrict__ cb,
                                                 const int* __restrict__ row_ptr,
                                                 int* __restrict__ col, int E, int nbw) {
    extern __shared__ unsigned hist[];
    int blk = blockIdx.x;
    for (int w = threadIdx.x; w < nbw; w += blockDim.x) hist[w] = 0;
    __syncthreads();
    const unsigned* pref = cb + (size_t)blk * nbw;
    int chunk = (E + gridDim.x - 1) / gridDim.x;
    int beg = blk * chunk;
    int end = min(E, beg + chunk);
    for (int e = beg + (int)threadIdx.x; e < end; e += blockDim.x) {
        int d = dst[e];
        unsigned sh = (unsigned)(d & 1) * 16u;
        unsigned old = atomicAdd(&hist[d >> 1], 1u << sh);
        unsigned lr = (old >> sh) & 0xffffu;
        unsigned pre = (pref[d >> 1] >> sh) & 0xffffu;
        int slot = row_ptr[d] + (int)pre + (int)lr;
        __builtin_nontemporal_store(src[e] << 7, &col[slot]);
    }
}

// ---------------- MFMA projection ----------------
// Block = 4 waves; wave 0..3 -> Q,K,V,S. A = W (frags resident), B = h.
// wave0: f16 q (pre-scaled by QSCALE). wave1/2: fp8-e4m3 into byte-
// interleaved 128B kv row (chunk c = k[c*8..+8] | v[c*8..+8] at byte c*16).
// wave3: skip + residual (read from f16 hbf), stored f16 into sb.
__global__ __launch_bounds__(256) void gemm_mfma(
    const unsigned short* __restrict__ hbf, const unsigned short* __restrict__ Wt,
    const float* __restrict__ Bq, const float* __restrict__ Bk,
    const float* __restrict__ Bv, const float* __restrict__ Bs,
    int with_res,
    unsigned short* __restrict__ qO, unsigned char* __restrict__ kvO,
    unsigned short* __restrict__ sO, int ntiles) {
    int lane = threadIdx.x & 63;
    int wave = threadIdx.x >> 6;
    int ml = lane & 15, ql = lane >> 4;

    const unsigned short* W = Wt + wave * 4096;
    h8 wfrag[4][2];     // A-frag: A[m=ml][k=ql*8+j] = Wt[t*16+ml][kh*32+ql*8+j]
#pragma unroll
    for (int t = 0; t < 4; ++t)
#pragma unroll
        for (int kh = 0; kh < 2; ++kh)
            wfrag[t][kh] = *(const h8*)(W + (t * 16 + ml) * 64 + kh * 32 + ql * 8);

    const float* bias = wave == 0 ? Bq : wave == 1 ? Bk : wave == 2 ? Bv : Bs;
    float4 bias4[4];
#pragma unroll
    for (int t = 0; t < 4; ++t) {
        bias4[t] = *(const float4*)(bias + t * 16 + ql * 4);
        if (wave == 0) {
            bias4[t].x *= QSCALE; bias4[t].y *= QSCALE;
            bias4[t].z *= QSCALE; bias4[t].w *= QSCALE;
        }
    }

    for (int tile = blockIdx.x; tile < ntiles; tile += gridDim.x) {
        int node0 = tile * 16;           // n = 50000 = 3125 * 16, no partial tile
        h8 hfrag[2];                     // B-frag: B[k=ql*8+j][n=ml]
#pragma unroll
        for (int kh = 0; kh < 2; ++kh)
            hfrag[kh] = *(const h8*)(hbf + (size_t)(node0 + ml) * 64 + kh * 32 + ql * 8);
        f32x4 acc[4];
#pragma unroll
        for (int t = 0; t < 4; ++t) {
            acc[t][0] = bias4[t].x; acc[t][1] = bias4[t].y;
            acc[t][2] = bias4[t].z; acc[t][3] = bias4[t].w;
        }
#pragma unroll
        for (int t = 0; t < 4; ++t)
#pragma unroll
            for (int kh = 0; kh < 2; ++kh)
                acc[t] = __builtin_amdgcn_mfma_f32_16x16x32_f16(
                    wfrag[t][kh], hfrag[kh], acc[t], 0, 0, 0);

        size_t rowe = (size_t)(node0 + ml) * 64;
        if (wave == 0) {
#pragma unroll
            for (int t = 0; t < 4; ++t) {
                uint2 st;
                st.x = pk2u(acc[t][0], acc[t][1]);
                st.y = pk2u(acc[t][2], acc[t][3]);
                *(uint2*)(qO + rowe + t * 16 + ql * 4) = st;
            }
        } else if (wave == 3) {
#pragma unroll
            for (int t = 0; t < 4; ++t) {
                float4 st = {acc[t][0], acc[t][1], acc[t][2], acc[t][3]};
                if (with_res) {
                    uint2 hv = *(const uint2*)(hbf + rowe + t * 16 + ql * 4);
                    h2 r0 = u2h2(hv.x), r1 = u2h2(hv.y);
                    st.x += (float)r0[0]; st.y += (float)r0[1];
                    st.z += (float)r1[0]; st.w += (float)r1[1];
                }
                uint2 sp;
                sp.x = pk2u(st.x, st.y);
                sp.y = pk2u(st.z, st.w);
                *(uint2*)(sO + rowe + t * 16 + ql * 4) = sp;
            }
        } else {
            // dims [t*16+ql*4, +4) -> chunk = t*2 + (ql>>1), byte (ql&1)*4
            size_t kvr = (size_t)(node0 + ml) * 128 + (wave == 2 ? 8 : 0);
#pragma unroll
            for (int t = 0; t < 4; ++t) {
                int pk = __builtin_amdgcn_cvt_pk_fp8_f32(acc[t][0], acc[t][1], 0, false);
                pk = __builtin_amdgcn_cvt_pk_fp8_f32(acc[t][2], acc[t][3], pk, true);
                size_t addr = kvr + (size_t)(t * 2 + (ql >> 1)) * 16 + (ql & 1) * 4;
                *(unsigned*)(kvO + addr) = (unsigned)pk;
            }
        }
    }
}

// ---------------- fused attention + LN ----------------
// One wave per dst node; 8 groups of 8 lanes; x2 volley (16 edge-slots).
// Byte-interleaved fp8 kv row: lane qi reads ONE uint4 (k-chunk | v-chunk).
// Logits carry log2(e) pre-scale -> p = exp2f(d). fp32 accum, LN+ReLU.
#define EDGE_COMP(U) do {                                                      \
    f32x2 k0 = __builtin_amdgcn_cvt_pk_f32_fp8((U).x, false);                  \
    f32x2 k1 = __builtin_amdgcn_cvt_pk_f32_fp8((U).x, true);                   \
    f32x2 k2 = __builtin_amdgcn_cvt_pk_f32_fp8((U).y, false);                  \
    f32x2 k3 = __builtin_amdgcn_cvt_pk_f32_fp8((U).y, true);                   \
    float d = qf0 * k0[0];                                                     \
    d = fmaf(qf1, k0[1], d); d = fmaf(qf2, k1[0], d); d = fmaf(qf3, k1[1], d); \
    d = fmaf(qf4, k2[0], d); d = fmaf(qf5, k2[1], d); d = fmaf(qf6, k3[0], d); \
    d = fmaf(qf7, k3[1], d);                                                   \
    d += __shfl_xor(d, 1); d += __shfl_xor(d, 2); d += __shfl_xor(d, 4);       \
    float p = exp2f(d); ssum += p;                                             \
    f32x2 w0 = __builtin_amdgcn_cvt_pk_f32_fp8((U).z, false);                  \
    f32x2 w1 = __builtin_amdgcn_cvt_pk_f32_fp8((U).z, true);                   \
    f32x2 w2 = __builtin_amdgcn_cvt_pk_f32_fp8((U).w, false);                  \
    f32x2 w3 = __builtin_amdgcn_cvt_pk_f32_fp8((U).w, true);                   \
    aa.x = fmaf(w0[0], p, aa.x); aa.y = fmaf(w0[1], p, aa.y);                  \
    aa.z = fmaf(w1[0], p, aa.z); aa.w = fmaf(w1[1], p, aa.w);                  \
    ab.x = fmaf(w2[0], p, ab.x); ab.y = fmaf(w2[1], p, ab.y);                  \
    ab.z = fmaf(w3[0], p, ab.z); ab.w = fmaf(w3[1], p, ab.w);                  \
} while (0)

__global__ __launch_bounds__(256) void attn_agg_ln(
    const unsigned short* __restrict__ qh, const unsigned char* __restrict__ kv,
    const unsigned short* __restrict__ sk,
    const int* __restrict__ row_ptr, const int* __restrict__ col,
    const float* __restrict__ g, const float* __restrict__ b,
    float* __restrict__ out, unsigned short* __restrict__ hbf_out, int n) {
    int node = blockIdx.x * 4 + (threadIdx.x >> 6);
    int lane = threadIdx.x & 63;
    if (node >= n) return;
    int grp = lane >> 3;
    int qi = lane & 7;

    size_t ro = (size_t)node * DD + qi * 8;
    uint4 qu = *(const uint4*)(qh + ro);          // 8 f16, pre-scaled QSCALE
    uint4 su = *(const uint4*)(sk + ro);          // 8 f16 skip(+residual)
    int beg = row_ptr[node], end = row_ptr[node + 1];

    // unpack q to 8 f32 once (feeds fp8-k fma chain)
    h2 q0 = u2h2(qu.x), q1 = u2h2(qu.y), q2 = u2h2(qu.z), q3 = u2h2(qu.w);
    float qf0 = (float)q0[0], qf1 = (float)q0[1], qf2 = (float)q1[0], qf3 = (float)q1[1];
    float qf4 = (float)q2[0], qf5 = (float)q2[1], qf6 = (float)q3[0], qf7 = (float)q3[1];

    float ssum = 0.0f;
    float4 aa = {0.f, 0.f, 0.f, 0.f}, ab = {0.f, 0.f, 0.f, 0.f};

    int e = beg + grp;
    int cv0 = (e < end) ? col[e] : -1;
    int cv1 = (e + 8 < end) ? col[e + 8] : -1;
    for (int e0 = beg; e0 < end; e0 += 16) {
        bool a0 = cv0 >= 0, a1 = cv1 >= 0;
        uint4 u0, u1;
        if (a0) u0 = *(const uint4*)(kv + cv0 + qi * 16);   // k|v chunk, one load
        if (a1) u1 = *(const uint4*)(kv + cv1 + qi * 16);
        e += 16;
        cv0 = (e < end) ? col[e] : -1;
        cv1 = (e + 8 < end) ? col[e + 8] : -1;
        if (a0) EDGE_COMP(u0);
        if (a1) EDGE_COMP(u1);
    }

#pragma unroll
    for (int off = 8; off <= 32; off <<= 1) {
        ssum += __shfl_xor(ssum, off);
        aa.x += __shfl_xor(aa.x, off); aa.y += __shfl_xor(aa.y, off);
        aa.z += __shfl_xor(aa.z, off); aa.w += __shfl_xor(aa.w, off);
        ab.x += __shfl_xor(ab.x, off); ab.y += __shfl_xor(ab.y, off);
        ab.z += __shfl_xor(ab.z, off); ab.w += __shfl_xor(ab.w, off);
    }
    float inv = (end > beg) ? 1.0f / ssum : 0.0f;
    aa.x *= inv; aa.y *= inv; aa.z *= inv; aa.w *= inv;
    ab.x *= inv; ab.y *= inv; ab.z *= inv; ab.w *= inv;

    {   // + skip (+ residual), f16 -> f32
        h2 t0 = u2h2(su.x), t1 = u2h2(su.y), t2 = u2h2(su.z), t3 = u2h2(su.w);
        aa.x += (float)t0[0]; aa.y += (float)t0[1];
        aa.z += (float)t1[0]; aa.w += (float)t1[1];
        ab.x += (float)t2[0]; ab.y += (float)t2[1];
        ab.z += (float)t3[0]; ab.w += (float)t3[1];
    }

    float s1 = aa.x + aa.y + aa.z + aa.w + ab.x + ab.y + ab.z + ab.w;
    s1 += __shfl_xor(s1, 1);
    s1 += __shfl_xor(s1, 2);
    s1 += __shfl_xor(s1, 4);
    float mu = s1 * (1.0f / DD);
    float dx0 = aa.x - mu, dx1 = aa.y - mu, dx2 = aa.z - mu, dx3 = aa.w - mu;
    float dx4 = ab.x - mu, dx5 = ab.y - mu, dx6 = ab.z - mu, dx7 = ab.w - mu;
    float s2v = dx0 * dx0 + dx1 * dx1 + dx2 * dx2 + dx3 * dx3
              + dx4 * dx4 + dx5 * dx5 + dx6 * dx6 + dx7 * dx7;
    s2v += __shfl_xor(s2v, 1);
    s2v += __shfl_xor(s2v, 2);
    s2v += __shfl_xor(s2v, 4);
    float var = s2v * (1.0f / DD);
    float is = rsqrtf(var + 1e-5f);
    float4 g4a = *(const float4*)(g + qi * 8);
    float4 g4b = *(const float4*)(g + qi * 8 + 4);
    float4 b4a = *(const float4*)(b + qi * 8);
    float4 b4b = *(const float4*)(b + qi * 8 + 4);
    float4 ya, yb;
    ya.x = fmaxf(dx0 * is * g4a.x + b4a.x, 0.0f);
    ya.y = fmaxf(dx1 * is * g4a.y + b4a.y, 0.0f);
    ya.z = fmaxf(dx2 * is * g4a.z + b4a.z, 0.0f);
    ya.w = fmaxf(dx3 * is * g4a.w + b4a.w, 0.0f);
    yb.x = fmaxf(dx4 * is * g4b.x + b4b.x, 0.0f);
    yb.y = fmaxf(dx5 * is * g4b.y + b4b.y, 0.0f);
    yb.z = fmaxf(dx6 * is * g4b.z + b4b.z, 0.0f);
    yb.w = fmaxf(dx7 * is * g4b.w + b4b.w, 0.0f);
    if (grp == 0) {
        if (out) {
            *(float4*)(out + ro) = ya;
            *(float4*)(out + ro + 4) = yb;
        }
        uint4 hv;
        hv.x = pk2u(ya.x, ya.y);
        hv.y = pk2u(ya.z, ya.w);
        hv.z = pk2u(yb.x, yb.y);
        hv.w = pk2u(yb.z, yb.w);
        *(uint4*)(hbf_out + ro) = hv;
    }
}

extern "C" void kernel_launch(void* const* d_in, const int* in_sizes, int n_in,
                              void* d_out, int out_size, void* d_ws, size_t ws_size,
                              hipStream_t stream) {
    const int D = DD;
    const float* x = (const float*)d_in[0];
    const int n = in_sizes[0] / D;       // 50000
    const int* ei = (const int*)d_in[1];
    const int E = in_sizes[1] / 2;       // 1e6
    const int* srcp = ei;
    const int* dstp = ei + E;
    const int nbw = (n + 1) / 2;         // bin-pair words (25000)

    static bool s_attr = false;
    if (!s_attr) {
        s_attr = true;
        (void)hipFuncSetAttribute((const void*)hist_prep,
                                  hipFuncAttributeMaxDynamicSharedMemorySize, 102400);
        (void)hipFuncSetAttribute((const void*)scatter2,
                                  hipFuncAttributeMaxDynamicSharedMemorySize, 102400);
    }

    char* wsp = (char*)d_ws;
    auto take = [&](size_t bytes) {
        char* p = wsp;
        wsp += (bytes + 255) & ~(size_t)255;
        return (void*)p;
    };
    int* counts    = (int*)take((size_t)n * 4);
    int* row_ptr   = (int*)take((size_t)(n + 1) * 4);
    unsigned* cb   = (unsigned*)take((size_t)NB_HIST * nbw * 4);   // 12.8 MB
    int* col       = (int*)take((size_t)E * 4);
    int* localscan = (int*)take((size_t)n * 4);
    int* blockSums = (int*)take((size_t)1024 * 4);
    size_t fsz = (size_t)n * D * 4;
    unsigned short* qb  = (unsigned short*)take(fsz / 2);   // f16 q (pre-scaled)
    unsigned char* kvb  = (unsigned char*)take(fsz / 2);    // fp8 k|v rows: n*128B
    unsigned short* sb  = (unsigned short*)take(fsz / 2);   // f16 skip+residual
    unsigned short* hbf = (unsigned short*)take(fsz / 2);   // f16 h (layer carrier)
    unsigned short* Wt  = (unsigned short*)take((size_t)16 * 4096 * 2);

    // ---- CSR build + prep (no global atomics) ----
    int tb = 256;
    size_t ldsH = (size_t)nbw * 4;       // 100 KB
    int nbScan = (n + 1023) / 1024;
    hist_prep<<<NB_HIST, 1024, ldsH, stream>>>(
        dstp, cb, E, nbw,
        x, hbf, n * D,
        (const float*)d_in[2], (const float*)d_in[4], (const float*)d_in[6],
        (const float*)d_in[8], (const float*)d_in[12], (const float*)d_in[14],
        (const float*)d_in[16], (const float*)d_in[18], Wt);
    prefix_blk<<<(nbw + tb - 1) / tb, tb, 0, stream>>>(cb, counts, nbw, n);
    scan_local<<<nbScan, 1024, 0, stream>>>(counts, localscan, blockSums, n);
    scan_tops<<<1, 64, 0, stream>>>(blockSums, nbScan);
    emit_rowptr<<<(n + tb - 1) / tb, tb, 0, stream>>>(localscan, blockSums, row_ptr, n, E);
    scatter2<<<NB_HIST, 1024, ldsH, stream>>>(srcp, dstp, cb, row_ptr, col, E, nbw);

    // ---- 4 conv layers ----
    int ntiles = n / 16;                 // 3125
    int nba = (n + 3) / 4;
    for (int layer = 0; layer < 4; ++layer) {
        const float *bq_, *bk_, *bv_, *bs_, *g_, *b_;
        if (layer == 0) {
            bq_ = (const float*)d_in[3];  bk_ = (const float*)d_in[5];
            bv_ = (const float*)d_in[7];  bs_ = (const float*)d_in[9];
            g_  = (const float*)d_in[10]; b_  = (const float*)d_in[11];
        } else {
            int i = layer - 1;
            bq_ = (const float*)d_in[13] + (size_t)i * D;
            bk_ = (const float*)d_in[15] + (size_t)i * D;
            bv_ = (const float*)d_in[17] + (size_t)i * D;
            bs_ = (const float*)d_in[19] + (size_t)i * D;
            g_  = (const float*)d_in[20] + (size_t)i * D;
            b_  = (const float*)d_in[21] + (size_t)i * D;
        }
        gemm_mfma<<<512, 256, 0, stream>>>(hbf, Wt + (size_t)layer * 4 * 4096,
                                           bq_, bk_, bv_, bs_,
                                           layer == 0 ? 0 : 1,
                                           qb, kvb, sb, ntiles);
        attn_agg_ln<<<nba, 256, 0, stream>>>(qb, kvb, sb, row_ptr, col, g_, b_,
                                             layer == 3 ? (float*)d_out : nullptr,
                                             hbf, n);
    }
}